// Round 3
// 302.469 us; speedup vs baseline: 1.0277x; 1.0277x over previous
//
#include <hip/hip_runtime.h>

// 16384 tokens x 128 experts router over hidden=2880, top-4 + softmax.
// GEMM via bf16 MFMA, 3-way split precision (x,w = h+m+l bf16; products
// hh,hm,mh,mm,hl,lh -> ~2^-22 relative error, fp32-class logits, exact top-k).
// This version: KSPLIT=6 (grid 768 = exactly 3 blocks/CU co-resident via
// __launch_bounds__(256,3), nit=15 even), hoisted k-loop address math,
// float2-vectorized topk kernel. (Resubmit of round-2 kernel: that round's
// bench failed on infrastructure, not the kernel.)
constexpr int T_TOK = 16384;
constexpr int NEXP  = 128;
constexpr int HID   = 2880;
constexpr int TOPK  = 4;

constexpr int KSPLIT = 6;             // 768 blocks = 3/CU, nit = 15 exactly
constexpr int KCH    = HID / 32;      // 90 k-chunks of 32
constexpr int NIT    = KCH / KSPLIT;  // 15 k-chunks per split
constexpr int BM     = 128;
constexpr int BK     = 32;
constexpr int WELEMS = NEXP * HID;

typedef __attribute__((ext_vector_type(8))) short bf16x8;
typedef __attribute__((ext_vector_type(4))) float f32x4;

__device__ inline void split3(float f, unsigned& hb, unsigned& mb, unsigned& lb) {
    unsigned u = __float_as_uint(f);
    unsigned rne = u + 0x7FFFu + ((u >> 16) & 1u);
    hb = rne & 0xFFFF0000u;
    float r = f - __uint_as_float(hb);
    mb = __float_as_uint(r) & 0xFFFF0000u;
    lb = __float_as_uint(r - __uint_as_float(mb));
}

// ---------------------------------------------------------------------------
// Kernel 0: split w into three bf16 planes in ws.
// ---------------------------------------------------------------------------
__global__ __launch_bounds__(256)
void w_split_kernel(const float* __restrict__ w, unsigned short* __restrict__ wh,
                    unsigned short* __restrict__ wm, unsigned short* __restrict__ wl) {
    int i = blockIdx.x * 256 + threadIdx.x;
    if (i < WELEMS) {
        unsigned hb, mb, lb;
        split3(w[i], hb, mb, lb);
        wh[i] = (unsigned short)(hb >> 16);
        wm[i] = (unsigned short)(mb >> 16);
        wl[i] = (unsigned short)(lb >> 16);
    }
}

// ---------------------------------------------------------------------------
// Kernel 1: MFMA split-K GEMM with double-buffered B-staging.
// Per iter: barrier (drains DMA/x issued last iter) -> issue DMA for it+1 into
// other buffer -> split current x regs -> prefetch x for it+1 -> 96 MFMAs.
// At 3 blocks/CU (12 waves), the MFMA round (~5.6K cyc) covers HBM latency of
// the 1-deep prefetches.
// ---------------------------------------------------------------------------
__global__ __launch_bounds__(256, 3)
void gemm_mfma(const float* __restrict__ x,
               const unsigned short* __restrict__ wh,
               const unsigned short* __restrict__ wm,
               const unsigned short* __restrict__ wl,
               float* __restrict__ part) {
    __shared__ unsigned short bs[2][3 * NEXP * BK];   // 2 x 24.6 KB

    const int tid  = threadIdx.x;
    const int wv   = tid >> 6;
    const int lane = tid & 63;
    const int lm   = lane & 15;
    const int lq   = lane >> 4;

    const int tile  = blockIdx.x / KSPLIT;
    const int split = blockIdx.x % KSPLIT;
    const int kcb   = NIT * split;        // first k-chunk; NIT iters each

    f32x4 acc[2][8];
#pragma unroll
    for (int i = 0; i < 2; ++i)
#pragma unroll
        for (int j = 0; j < 8; ++j) acc[i][j] = (f32x4){0.f, 0.f, 0.f, 0.f};

    const float* xb = x + (size_t)tile * BM * HID;

    // Hoisted staging sources: LDS chunk index is iter-invariant; global src
    // advances by 32 elements (64 B) per iter. 3 planes x 128 experts x 32 =
    // 1536 16B-chunks, 6/thread; each wave's 64 chunks contiguous in LDS.
    const unsigned short* srcp[6];
    int cidx[6];
#pragma unroll
    for (int r = 0; r < 6; ++r) {
        const int c  = (r * 4 + wv) * 64 + lane;   // 0..1535
        const int cc = c & 511;
        const int e  = cc >> 2;
        const int kq = (cc & 3) << 3;
        const unsigned short* plane = (r < 2) ? wh : (r < 4) ? wm : wl;
        srcp[r] = plane + (size_t)e * HID + kcb * 32 + kq;
        cidx[r] = c;
    }
    const float* xp[2];
#pragma unroll
    for (int i = 0; i < 2; ++i)
        xp[i] = xb + (size_t)(wv * 32 + i * 16 + lm) * HID + kcb * 32 + lq * 8;

    auto stage = [&](int it, int buf) {
#pragma unroll
        for (int r = 0; r < 6; ++r) {
            __builtin_amdgcn_global_load_lds(
                (const __attribute__((address_space(1))) void*)(srcp[r] + it * 32),
                (__attribute__((address_space(3))) void*)&bs[buf][cidx[r] * 8], 16, 0, 0);
        }
    };
    auto loadx = [&](int it, float4 xr[2][2]) {
#pragma unroll
        for (int i = 0; i < 2; ++i) {
            const float* ap = xp[i] + it * 32;
            xr[i][0] = *reinterpret_cast<const float4*>(ap);
            xr[i][1] = *reinterpret_cast<const float4*>(ap + 4);
        }
    };

    float4 xr[2][2];
    stage(0, 0);
    loadx(0, xr);

#pragma unroll 1
    for (int it = 0; it < NIT; ++it) {
        const int cur = it & 1;
        __syncthreads();                    // drains DMA/loads for this iter
        if (it + 1 < NIT) stage(it + 1, cur ^ 1);

        // split current x into packed bf16 h/m/l A-fragments
        unsigned ah[2][4], am[2][4], al[2][4];
#pragma unroll
        for (int i = 0; i < 2; ++i) {
            float fv[8] = {xr[i][0].x, xr[i][0].y, xr[i][0].z, xr[i][0].w,
                           xr[i][1].x, xr[i][1].y, xr[i][1].z, xr[i][1].w};
            unsigned hb[8], mb[8], lb[8];
#pragma unroll
            for (int e2 = 0; e2 < 8; ++e2) split3(fv[e2], hb[e2], mb[e2], lb[e2]);
#pragma unroll
            for (int p = 0; p < 4; ++p) {
                ah[i][p] = __builtin_amdgcn_perm(hb[2*p+1], hb[2*p], 0x07060302u);
                am[i][p] = __builtin_amdgcn_perm(mb[2*p+1], mb[2*p], 0x07060302u);
                al[i][p] = __builtin_amdgcn_perm(lb[2*p+1], lb[2*p], 0x07060302u);
            }
        }
        if (it + 1 < NIT) loadx(it + 1, xr);   // in flight across MFMA block

#pragma unroll
        for (int j = 0; j < 8; ++j) {
            const int boff = (j * 16 + lm) * BK + lq * 8;
            bf16x8 Bh = *reinterpret_cast<const bf16x8*>(&bs[cur][boff]);
            bf16x8 Bm = *reinterpret_cast<const bf16x8*>(&bs[cur][NEXP * BK + boff]);
            bf16x8 Bl = *reinterpret_cast<const bf16x8*>(&bs[cur][2 * NEXP * BK + boff]);
#pragma unroll
            for (int i = 0; i < 2; ++i) {
                union { unsigned u[4]; bf16x8 v; } Ah, Am, Al;
#pragma unroll
                for (int p = 0; p < 4; ++p) {
                    Ah.u[p] = ah[i][p]; Am.u[p] = am[i][p]; Al.u[p] = al[i][p];
                }
                acc[i][j] = __builtin_amdgcn_mfma_f32_16x16x32_bf16(Ah.v, Bh, acc[i][j], 0, 0, 0);
                acc[i][j] = __builtin_amdgcn_mfma_f32_16x16x32_bf16(Ah.v, Bm, acc[i][j], 0, 0, 0);
                acc[i][j] = __builtin_amdgcn_mfma_f32_16x16x32_bf16(Am.v, Bh, acc[i][j], 0, 0, 0);
                acc[i][j] = __builtin_amdgcn_mfma_f32_16x16x32_bf16(Am.v, Bm, acc[i][j], 0, 0, 0);
                acc[i][j] = __builtin_amdgcn_mfma_f32_16x16x32_bf16(Ah.v, Bl, acc[i][j], 0, 0, 0);
                acc[i][j] = __builtin_amdgcn_mfma_f32_16x16x32_bf16(Al.v, Bh, acc[i][j], 0, 0, 0);
            }
        }
    }

    // C/D layout: col = lane&15, row = quad*4 + reg
#pragma unroll
    for (int i = 0; i < 2; ++i) {
        const int trow = tile * BM + wv * 32 + i * 16 + lq * 4;
#pragma unroll
        for (int j = 0; j < 8; ++j) {
            const int e = j * 16 + lm;
            float* p = part + ((size_t)split * T_TOK + trow) * NEXP + e;
#pragma unroll
            for (int r = 0; r < 4; ++r) p[(size_t)r * NEXP] = acc[i][j][r];
        }
    }
}

// ---------------------------------------------------------------------------
// Kernel 2: reduce splits + bias (+vision bias), top-4 (tie -> lower index),
// softmax over 4, dense scatter + indices (as float). One wave per token.
// Each lane owns the adjacent expert pair (2*lane, 2*lane+1) -> float2 loads.
// ---------------------------------------------------------------------------
__global__ __launch_bounds__(256)
void topk_scatter(const float* __restrict__ part, const int* __restrict__ mm,
                  const float* __restrict__ bias, const float* __restrict__ vbias,
                  float* __restrict__ out) {
    const int lane = threadIdx.x & 63;
    const int wid  = threadIdx.x >> 6;
    const int t    = blockIdx.x * 4 + wid;

    const int e0 = 2 * lane, e1 = 2 * lane + 1;
    float2 b2 = *reinterpret_cast<const float2*>(&bias[e0]);
    float v0 = b2.x, v1 = b2.y;
    if (mm[t] != 0) {
        float2 vb2 = *reinterpret_cast<const float2*>(&vbias[e0]);
        v0 += vb2.x; v1 += vb2.y;
    }
#pragma unroll
    for (int s = 0; s < KSPLIT; ++s) {
        const float* p = part + ((size_t)s * T_TOK + t) * NEXP;
        float2 pv = *reinterpret_cast<const float2*>(&p[e0]);
        v0 += pv.x;
        v1 += pv.y;
    }

    float lv0 = v0, lv1 = v1;
    float tv[TOPK];
    int   ti[TOPK];
#pragma unroll
    for (int k = 0; k < TOPK; ++k) {
        float bv; int bi;
        if (lv0 >= lv1) { bv = lv0; bi = e0; }
        else            { bv = lv1; bi = e1; }
#pragma unroll
        for (int off = 32; off >= 1; off >>= 1) {
            float ov = __shfl_xor(bv, off, 64);
            int   oi = __shfl_xor(bi, off, 64);
            if (ov > bv || (ov == bv && oi < bi)) { bv = ov; bi = oi; }
        }
        tv[k] = bv;
        ti[k] = bi;
        if (bi == e0) lv0 = -__builtin_inff();
        if (bi == e1) lv1 = -__builtin_inff();
    }

    const float m = tv[0];
    float ex[TOPK], s = 0.f;
#pragma unroll
    for (int k = 0; k < TOPK; ++k) { ex[k] = expf(tv[k] - m); s += ex[k]; }
    const float inv = 1.0f / s;

    float s0 = 0.f, s1 = 0.f;
#pragma unroll
    for (int k = 0; k < TOPK; ++k) {
        const float p = ex[k] * inv;
        if (ti[k] == e0) s0 = p;
        if (ti[k] == e1) s1 = p;
    }
    *reinterpret_cast<float2*>(&out[(size_t)t * NEXP + e0]) = make_float2(s0, s1);
    if (lane < TOPK)
        out[(size_t)T_TOK * NEXP + (size_t)t * TOPK + lane] = (float)ti[lane];
}

extern "C" void kernel_launch(void* const* d_in, const int* in_sizes, int n_in,
                              void* d_out, int out_size, void* d_ws, size_t ws_size,
                              hipStream_t stream) {
    const float* x     = (const float*)d_in[0];   // (4,4096,2880) fp32
    const int*   mm    = (const int*)d_in[1];     // (4,4096) bool -> int32
    const float* w     = (const float*)d_in[2];   // (128,2880) fp32
    const float* bias  = (const float*)d_in[3];   // (128,)
    const float* vbias = (const float*)d_in[4];   // (128,)
    float* out  = (float*)d_out;                  // [scores 16384*128 | idx 16384*4]

    // ws: partials (6*16384*128 fp32 = 50.3 MB) | wh | wm | wl bf16 planes
    float* part = (float*)d_ws;
    const size_t part_bytes = (size_t)KSPLIT * T_TOK * NEXP * sizeof(float);
    unsigned short* whp = (unsigned short*)((char*)d_ws + part_bytes);
    unsigned short* wmp = whp + WELEMS;
    unsigned short* wlp = wmp + WELEMS;

    hipLaunchKernelGGL(w_split_kernel, dim3((WELEMS + 255) / 256), dim3(256), 0,
                       stream, w, whp, wmp, wlp);
    hipLaunchKernelGGL(gemm_mfma, dim3((T_TOK / BM) * KSPLIT), dim3(256), 0, stream,
                       x, whp, wmp, wlp, part);
    hipLaunchKernelGGL(topk_scatter, dim3(T_TOK / 4), dim3(256), 0, stream,
                       part, mm, bias, vbias, out);
}